// Round 4
// baseline (1105.126 us; speedup 1.0000x reference)
//
// CentroidLayer (Karcher-flow centroid update) — MI355X fp32 implementation.
//
// R4 = R3 (never benched: infra timeout) + wave_barrier hardening:
//  - Single-wave workgroups run with NO __syncthreads (no waitcnt drains,
//    prefetch stays in flight). Hardware executes a wave's LDS ops in order,
//    but compiler alias analysis is per-thread and could reorder a lane's
//    ds_read above a prior ds_write feeding it cross-lane. Every LDS-reading
//    helper therefore begins with __builtin_amdgcn_wave_barrier() — a
//    scheduling-only pseudo-op (zero ISA bytes) pinning program order.
//  - stage_b: 2048 WGs (16 jobs each), 20KB LDS -> 8 WG/CU (2 waves/SIMD);
//    X tile for job jb+1 prefetched into registers at the top of job jb.
//    Host falls back to 1024 WGs if ws_size is too small for the partials.
// Algorithm (unchanged):
//  - stage_a: per group g (32): C^{-1/2}, C^{+1/2} via Chebyshev polys of
//    1/(sqrt(x)+1e-9) and sqrt(x) on [0.45, ||C||inf*1.02] (Clenshaw, coeffs
//    by 64-node Chebyshev quadrature). Stores aC[g] = 0.48/||C||inf, a
//    rigorous eig(M) lower bound (X >= 0.5 I by construction).
//  - stage_b: 32768 jobs: M = Cm05*X*Cm05 (SPD), log(M) as degree-29
//    Chebyshev series, closed-form coeffs c_k = -2(-z)^k/k on per-job
//    [aC, ||M||inf], Paterson-Stockmeyer folding
//    (T_{6j+i} = 2 T_i T_{6j} - T_{6j-i}) => 14 matmuls/job. Deterministic
//    per-WG partial sums (no atomics).
//  - stage_c: L_m = eta*mean(log); E = matfun(L_m, exp) = sign(L)*exp(|L|):
//    K = sign(L_m) via 28 Newton-Schulz iters, E = K*expm(K*L_m) (4-term
//    Taylor). C_new = Cp05 * (E * Cp05).
//  - Matmul micro-kernel: 1 wave per 32x32 job, operands in LDS, lane
//    (lr,lc) owns a 4x4 tile; A operands are all symmetric so both fragment
//    loads are contiguous ds_read_b128 with 8-way broadcast (conflict-free).

#include <hip/hip_runtime.h>
#include <math.h>

#define DEV static __device__ __forceinline__

namespace {

constexpr int    MSZ   = 1024;           // 32*32
constexpr int    NGRP  = 32;             // CLS*N
constexpr int    NB    = 1024;           // sampled batch count
constexpr int    XROW  = NGRP * MSZ;     // 32768 floats per batch row of X

// ws layout (float offsets)
constexpr size_t WS_CM05 = 0;                      // [32][1024]
constexpr size_t WS_CP05 = WS_CM05 + NGRP * MSZ;   // [32][1024]
constexpr size_t WS_AC   = WS_CP05 + NGRP * MSZ;   // [32]
constexpr size_t WS_PART = 131072;                 // [nwgb][1024]

// Scheduling-only barrier: pins LDS write->read program order for the
// in-order per-wave LDS pipe. Emits no machine instruction.
DEV void wbar() { __builtin_amdgcn_wave_barrier(); }

// C[r0+i][c0+j] = sum_k A[r0+i][k]*B[k][c0+j]; A is read transposed-via-
// symmetry (A[r][k] == A[k][r]), so both fragment loads are contiguous
// float4 in row k (8-way broadcast within the wave, conflict-free).
DEV void mm32(const float* __restrict__ A, const float* __restrict__ B,
              int r0, int c0, float acc[4][4]) {
  wbar();  // order after any prior LDS writes feeding A/B cross-lane
#pragma unroll
  for (int i = 0; i < 4; ++i)
#pragma unroll
    for (int j = 0; j < 4; ++j) acc[i][j] = 0.0f;
#pragma unroll 8
  for (int k = 0; k < 32; ++k) {
    const float4 av = *(const float4*)(A + (k << 5) + r0);
    const float4 bv = *(const float4*)(B + (k << 5) + c0);
    const float a[4] = {av.x, av.y, av.z, av.w};
    const float b[4] = {bv.x, bv.y, bv.z, bv.w};
#pragma unroll
    for (int i = 0; i < 4; ++i)
#pragma unroll
      for (int j = 0; j < 4; ++j) acc[i][j] = fmaf(a[i], b[j], acc[i][j]);
  }
}

DEV void twrite(float* D, int r0, int c0, const float t[4][4]) {
#pragma unroll
  for (int i = 0; i < 4; ++i) {
    float4 v;
    v.x = t[i][0]; v.y = t[i][1]; v.z = t[i][2]; v.w = t[i][3];
    *(float4*)(D + ((r0 + i) << 5) + c0) = v;
  }
}

DEV void tread(const float* M, int r0, int c0, float t[4][4]) {
  wbar();
#pragma unroll
  for (int i = 0; i < 4; ++i) {
    const float4 v = *(const float4*)(M + ((r0 + i) << 5) + c0);
    t[i][0] = v.x; t[i][1] = v.y; t[i][2] = v.z; t[i][3] = v.w;
  }
}

DEV void taccum(float S[4][4], const float a[4][4]) {
#pragma unroll
  for (int i = 0; i < 4; ++i)
#pragma unroll
    for (int j = 0; j < 4; ++j) S[i][j] += a[i][j];
}

DEV float wsum(float v) {
#pragma unroll
  for (int m = 1; m < 64; m <<= 1) v += __shfl_xor(v, m);
  return v;
}

DEV void g2l_mat(float* dst, const float* src, int lane) {
#pragma unroll
  for (int q = 0; q < 4; ++q) {
    const int off = q * 256 + lane * 4;
    *(float4*)(dst + off) = *(const float4*)(src + off);
  }
  wbar();
}

DEV void g2r(float4 xp[4], const float* src, int lane) {
#pragma unroll
  for (int q = 0; q < 4; ++q) xp[q] = *(const float4*)(src + q * 256 + lane * 4);
}

DEV void r2l(float* dst, const float4 xp[4], int lane) {
#pragma unroll
  for (int q = 0; q < 4; ++q) *(float4*)(dst + q * 256 + lane * 4) = xp[q];
  wbar();
}

}  // namespace

// ---------------------------------------------------------------------------
// stage_a: per-group C^{-1/2}, C^{+1/2}, and eig(M) lower bound aC.
// Single-wave WG: no runtime barriers (same-wave DS ops are in order).
// ---------------------------------------------------------------------------
__global__ void __launch_bounds__(64, 1)
centroid_stage_a(const float* __restrict__ Cin, float* __restrict__ ws) {
  __shared__ float lds[4 * MSZ];
  __shared__ float coefs[2][21];
  float* CM = lds;
  float* TT = lds + MSZ;
  float* B1 = lds + 2 * MSZ;
  float* B2 = lds + 3 * MSZ;

  const int lane = threadIdx.x;
  const int lr = lane >> 3, lc = lane & 7;
  const int r0 = lr << 2, c0 = lc << 2;
  const bool dg = (lr == lc);
  const int g = blockIdx.x;

  g2l_mat(CM, Cin + (size_t)g * MSZ, lane);

  // ||C||inf (>= lambda_max for symmetric C)
  float tC[4][4];
  tread(CM, r0, c0, tC);
  float rs[4];
#pragma unroll
  for (int i = 0; i < 4; ++i)
    rs[i] = fabsf(tC[i][0]) + fabsf(tC[i][1]) + fabsf(tC[i][2]) + fabsf(tC[i][3]);
#pragma unroll
  for (int m = 1; m < 8; m <<= 1) {
#pragma unroll
    for (int i = 0; i < 4; ++i) rs[i] += __shfl_xor(rs[i], m);
  }
  float mx = fmaxf(fmaxf(rs[0], rs[1]), fmaxf(rs[2], rs[3]));
#pragma unroll
  for (int m = 8; m < 64; m <<= 1) mx = fmaxf(mx, __shfl_xor(mx, m));

  const float aR = 0.45f;           // lambda_min(C) >= 0.5 by construction
  const float bR = mx * 1.02f;
  const float alpha = 0.5f * (aR + bR), beta = 0.5f * (bR - aR);

  if (lane == 0) ws[WS_AC + g] = 0.48f / bR;  // rigorous lower bound for eig(M)

  // Chebyshev coefficients of f on [aR,bR] by 64-node quadrature (libm cosf:
  // args reach ~63 rad, __cosf range reduction is too sloppy).
  const float theta = ((float)lane + 0.5f) * (3.14159265358979323846f / 64.0f);
  const float xn = alpha + beta * cosf(theta);
  const float sq = sqrtf(xn);
  const float f1 = 1.0f / (sq + 1e-9f);  // -> Cm05   (matches ref's eps)
  const float f2 = sq;                   // -> Cp05
  for (int k = 0; k <= 20; ++k) {
    const float ck = cosf((float)k * theta);
    const float s1 = wsum(f1 * ck);
    const float s2 = wsum(f2 * ck);
    if (lane == 0) {
      const float sc = (k == 0) ? (1.0f / 64.0f) : (2.0f / 64.0f);
      coefs[0][k] = s1 * sc;
      coefs[1][k] = s2 * sc;
    }
  }
  wbar();

  // TT = (C - alpha I)/beta
  {
    const float invb = 1.0f / beta;
    float t[4][4];
#pragma unroll
    for (int i = 0; i < 4; ++i)
#pragma unroll
      for (int j = 0; j < 4; ++j) {
        float v = tC[i][j];
        if (dg && i == j) v -= alpha;
        t[i][j] = v * invb;
      }
    twrite(TT, r0, c0, t);
  }

  // Two Clenshaw evaluations (degree 20)
  for (int f = 0; f < 2; ++f) {
    const float* cf = coefs[f];
    {
      float tI[4][4], tZ[4][4];
#pragma unroll
      for (int i = 0; i < 4; ++i)
#pragma unroll
        for (int j = 0; j < 4; ++j) {
          tI[i][j] = (dg && i == j) ? cf[20] : 0.0f;
          tZ[i][j] = 0.0f;
        }
      twrite(B1, r0, c0, tI);
      twrite(B2, r0, c0, tZ);
    }
    float* cur = B1;
    float* prev = B2;
    for (int k = 19; k >= 1; --k) {
      float acc[4][4];
      mm32(TT, cur, r0, c0, acc);
      const float ck = cf[k];
      float pt[4][4];
      tread(prev, r0, c0, pt);
      float nt[4][4];
#pragma unroll
      for (int i = 0; i < 4; ++i)
#pragma unroll
        for (int j = 0; j < 4; ++j) {
          float v = 2.0f * acc[i][j] - pt[i][j];
          if (dg && i == j) v += ck;
          nt[i][j] = v;
        }
      wbar();  // all lanes' reads of prev precede this overwrite
      twrite(prev, r0, c0, nt);
      float* tmp = cur; cur = prev; prev = tmp;
    }
    float acc[4][4];
    mm32(TT, cur, r0, c0, acc);
    float pt[4][4];
    tread(prev, r0, c0, pt);
    float* dst = ws + ((f == 0) ? WS_CM05 : WS_CP05) + (size_t)g * MSZ;
#pragma unroll
    for (int i = 0; i < 4; ++i) {
      float4 v4;
      float vv[4];
#pragma unroll
      for (int j = 0; j < 4; ++j) {
        float v = acc[i][j] - pt[i][j];
        if (dg && i == j) v += cf[0];
        vv[j] = v;
      }
      v4.x = vv[0]; v4.y = vv[1]; v4.z = vv[2]; v4.w = vv[3];
      *(float4*)(dst + ((r0 + i) << 5) + c0) = v4;
    }
    wbar();
  }
}

// ---------------------------------------------------------------------------
// stage_b: (32<<sh) WGs x (NB>>sh) jobs: sum of log(Cm05 X_b Cm05).
// LDS 5 x 4KB = 20KB -> 8 WG/CU. Buffers:
//   CM | B0 (X -> V -> T18) | B1 (T1 -> T6) | B2 (T2/T4 -> H_j) | B3
//   (T3/T5 -> T12 -> T24). T1..T5, T6, T12 also live in registers.
// Single-wave WG: no runtime barriers; X prefetched to registers.
// ---------------------------------------------------------------------------
__global__ void __launch_bounds__(64, 1)
centroid_stage_b(const float* __restrict__ X, const int* __restrict__ idx,
                 const float* __restrict__ ws, float* __restrict__ partials,
                 int sh) {
  __shared__ float lds[5 * MSZ];  // 20 KB
  float* CM = lds;
  float* B0 = lds + MSZ;
  float* B1 = lds + 2 * MSZ;
  float* B2 = lds + 3 * MSZ;
  float* B3 = lds + 4 * MSZ;

  const int lane = threadIdx.x;
  const int lr = lane >> 3, lc = lane & 7;
  const int r0 = lr << 2, c0 = lc << 2;
  const bool dg = (lr == lc);

  const int w = blockIdx.x;
  const int g = w >> sh;
  const int njpw = NB >> sh;
  const int b0 = (w & ((1 << sh) - 1)) * njpw;

  g2l_mat(CM, ws + WS_CM05 + (size_t)g * MSZ, lane);
  const float aB = ws[WS_AC + g];

  float S[4][4];
#pragma unroll
  for (int i = 0; i < 4; ++i)
#pragma unroll
    for (int j = 0; j < 4; ++j) S[i][j] = 0.0f;

  float4 xp[4];
  g2r(xp, X + (size_t)idx[b0] * XROW + (size_t)g * MSZ, lane);

  for (int jb = 0; jb < njpw; ++jb) {
    r2l(B0, xp, lane);  // X tile -> LDS
    // prefetch next job's X into registers (hidden under this job's compute)
    {
      const int jn = (jb + 1 < njpw) ? (jb + 1) : jb;
      g2r(xp, X + (size_t)idx[b0 + jn] * XROW + (size_t)g * MSZ, lane);
    }

    float acc[4][4];

    // V = X * Cm05 -> B0 (in place; wave-lockstep makes reads precede writes)
    mm32(B0, CM, r0, c0, acc);
    wbar();
    twrite(B0, r0, c0, acc);

    // M = Cm05 * V  (SPD); range + coefficients + T1
    mm32(CM, B0, r0, c0, acc);

    float rs[4];
#pragma unroll
    for (int i = 0; i < 4; ++i)
      rs[i] = fabsf(acc[i][0]) + fabsf(acc[i][1]) + fabsf(acc[i][2]) + fabsf(acc[i][3]);
#pragma unroll
    for (int m = 1; m < 8; m <<= 1) {
#pragma unroll
      for (int i = 0; i < 4; ++i) rs[i] += __shfl_xor(rs[i], m);
    }
    float mxv = fmaxf(fmaxf(rs[0], rs[1]), fmaxf(rs[2], rs[3]));
#pragma unroll
    for (int m = 8; m < 64; m <<= 1) mxv = fmaxf(mxv, __shfl_xor(mxv, m));
    const float bB = mxv * 1.001f + 1e-6f;  // ||M||inf >= lambda_max

    const float alpha = 0.5f * (aB + bB);
    const float beta = 0.5f * (bB - aB);
    const float wq = beta / alpha;
    const float zq = wq / (1.0f + sqrtf(fmaxf(1.0f - wq * wq, 0.0f)));

    // closed-form Chebyshev coeffs of log on [aB,bB]; fold for PS scheme
    float cp[30];
    cp[0] = logf(alpha) - log1pf(zq * zq);
    {
      const float tz = -zq;
      float tp = tz;
#pragma unroll
      for (int k = 1; k < 30; ++k) {
        cp[k] = -2.0f * tp * (1.0f / (float)k);
        tp *= tz;
      }
    }
#pragma unroll
    for (int j = 4; j >= 1; --j) {
#pragma unroll
      for (int i = 1; i <= 5; ++i) cp[6 * j - i] -= cp[6 * j + i];
    }

    const float invb = 1.0f / beta;
    float T1t[4][4], T2t[4][4], T3t[4][4], T4t[4][4], T5t[4][4], T6t[4][4], T12t[4][4];

    // T1 = (M - alpha I)/beta -> B1 ; S += cp0*I + cp1*T1
#pragma unroll
    for (int i = 0; i < 4; ++i)
#pragma unroll
      for (int j = 0; j < 4; ++j) {
        float v = acc[i][j];
        if (dg && i == j) v -= alpha;
        v *= invb;
        T1t[i][j] = v;
        S[i][j] += cp[1] * v;
        if (dg && i == j) S[i][j] += cp[0];
      }
    twrite(B1, r0, c0, T1t);

    // T2 = 2 T1*T1 - I  -> B2
    mm32(B1, B1, r0, c0, acc);
#pragma unroll
    for (int i = 0; i < 4; ++i)
#pragma unroll
      for (int j = 0; j < 4; ++j) {
        float v = 2.0f * acc[i][j] - ((dg && i == j) ? 1.0f : 0.0f);
        T2t[i][j] = v;
        S[i][j] += cp[2] * v;
      }
    twrite(B2, r0, c0, T2t);

    // T3 = 2 T1*T2 - T1  -> B3
    mm32(B1, B2, r0, c0, acc);
#pragma unroll
    for (int i = 0; i < 4; ++i)
#pragma unroll
      for (int j = 0; j < 4; ++j) {
        float v = 2.0f * acc[i][j] - T1t[i][j];
        T3t[i][j] = v;
        S[i][j] += cp[3] * v;
      }
    twrite(B3, r0, c0, T3t);

    // T4 = 2 T1*T3 - T2  -> B2 (T2 lives in registers)
    mm32(B1, B3, r0, c0, acc);
#pragma unroll
    for (int i = 0; i < 4; ++i)
#pragma unroll
      for (int j = 0; j < 4; ++j) {
        float v = 2.0f * acc[i][j] - T2t[i][j];
        T4t[i][j] = v;
        S[i][j] += cp[4] * v;
      }
    wbar();
    twrite(B2, r0, c0, T4t);

    // T5 = 2 T1*T4 - T3  -> B3 (T3 in registers)
    mm32(B1, B2, r0, c0, acc);
#pragma unroll
    for (int i = 0; i < 4; ++i)
#pragma unroll
      for (int j = 0; j < 4; ++j) {
        float v = 2.0f * acc[i][j] - T3t[i][j];
        T5t[i][j] = v;
        S[i][j] += cp[5] * v;
      }
    wbar();
    twrite(B3, r0, c0, T5t);

    // T6 = 2 T1*T5 - T4  -> B1 (overwrites T1; T1 in registers)
    mm32(B1, B3, r0, c0, acc);
#pragma unroll
    for (int i = 0; i < 4; ++i)
#pragma unroll
      for (int j = 0; j < 4; ++j) {
        float v = 2.0f * acc[i][j] - T4t[i][j];
        T6t[i][j] = v;
        S[i][j] += cp[6] * v;
      }
    wbar();
    twrite(B1, r0, c0, T6t);

    // ---- j=1: H1 -> B2; S += T6*H1; T12 = 2 T6*T6 - I -> B3
    {
      float h[4][4];
#pragma unroll
      for (int i = 0; i < 4; ++i)
#pragma unroll
        for (int j = 0; j < 4; ++j)
          h[i][j] = 2.0f * (cp[7] * T1t[i][j] + cp[8] * T2t[i][j] + cp[9] * T3t[i][j] +
                            cp[10] * T4t[i][j] + cp[11] * T5t[i][j]);
      wbar();
      twrite(B2, r0, c0, h);
    }
    mm32(B1, B2, r0, c0, acc);
    taccum(S, acc);
    mm32(B1, B1, r0, c0, acc);
#pragma unroll
    for (int i = 0; i < 4; ++i)
#pragma unroll
      for (int j = 0; j < 4; ++j) {
        float v = 2.0f * acc[i][j] - ((dg && i == j) ? 1.0f : 0.0f);
        T12t[i][j] = v;
        S[i][j] += cp[12] * v;
      }
    wbar();
    twrite(B3, r0, c0, T12t);

    // ---- j=2: H2 -> B2; S += T12*H2; T18 = 2 T6*T12 - T6 -> B0
    {
      float h[4][4];
#pragma unroll
      for (int i = 0; i < 4; ++i)
#pragma unroll
        for (int j = 0; j < 4; ++j)
          h[i][j] = 2.0f * (cp[13] * T1t[i][j] + cp[14] * T2t[i][j] + cp[15] * T3t[i][j] +
                            cp[16] * T4t[i][j] + cp[17] * T5t[i][j]);
      wbar();
      twrite(B2, r0, c0, h);
    }
    mm32(B3, B2, r0, c0, acc);
    taccum(S, acc);
    mm32(B1, B3, r0, c0, acc);
    {
      float v2[4][4];
#pragma unroll
      for (int i = 0; i < 4; ++i)
#pragma unroll
        for (int j = 0; j < 4; ++j) {
          float v = 2.0f * acc[i][j] - T6t[i][j];
          v2[i][j] = v;
          S[i][j] += cp[18] * v;
        }
      wbar();
      twrite(B0, r0, c0, v2);
    }

    // ---- j=3: H3 -> B2; S += T18*H3; T24 = 2 T6*T18 - T12 -> B3
    {
      float h[4][4];
#pragma unroll
      for (int i = 0; i < 4; ++i)
#pragma unroll
        for (int j = 0; j < 4; ++j)
          h[i][j] = 2.0f * (cp[19] * T1t[i][j] + cp[20] * T2t[i][j] + cp[21] * T3t[i][j] +
                            cp[22] * T4t[i][j] + cp[23] * T5t[i][j]);
      wbar();
      twrite(B2, r0, c0, h);
    }
    mm32(B0, B2, r0, c0, acc);
    taccum(S, acc);
    mm32(B1, B0, r0, c0, acc);
    {
      float v2[4][4];
#pragma unroll
      for (int i = 0; i < 4; ++i)
#pragma unroll
        for (int j = 0; j < 4; ++j) {
          float v = 2.0f * acc[i][j] - T12t[i][j];
          v2[i][j] = v;
          S[i][j] += cp[24] * v;
        }
      wbar();
      twrite(B3, r0, c0, v2);
    }

    // ---- j=4: H4 -> B2; S += T24*H4
    {
      float h[4][4];
#pragma unroll
      for (int i = 0; i < 4; ++i)
#pragma unroll
        for (int j = 0; j < 4; ++j)
          h[i][j] = 2.0f * (cp[25] * T1t[i][j] + cp[26] * T2t[i][j] + cp[27] * T3t[i][j] +
                            cp[28] * T4t[i][j] + cp[29] * T5t[i][j]);
      wbar();
      twrite(B2, r0, c0, h);
    }
    mm32(B3, B2, r0, c0, acc);
    taccum(S, acc);
    wbar();  // all reads done before next job's r2l overwrites B0
  }

  // partial sum out (deterministic reduction in stage_c)
  {
    float* dst = partials + (size_t)w * MSZ;
#pragma unroll
    for (int i = 0; i < 4; ++i) {
      float4 v4;
      v4.x = S[i][0]; v4.y = S[i][1]; v4.z = S[i][2]; v4.w = S[i][3];
      *(float4*)(dst + ((r0 + i) << 5) + c0) = v4;
    }
  }
}

// ---------------------------------------------------------------------------
// stage_c: per group: L_m; K=sign(L_m) (Newton-Schulz); E=K*exp(K L_m);
//          C_new = Cp05 * (E * Cp05). Single-wave WG, no runtime barriers.
// ---------------------------------------------------------------------------
__global__ void __launch_bounds__(64, 1)
centroid_stage_c(const float* __restrict__ ws, float* __restrict__ out, int sh) {
  __shared__ float lds[5 * MSZ];
  float* Lm = lds;
  float* Ss = lds + MSZ;
  float* Ts = lds + 2 * MSZ;
  float* Us = lds + 3 * MSZ;
  float* Wsl = lds + 4 * MSZ;

  const int lane = threadIdx.x;
  const int lr = lane >> 3, lc = lane & 7;
  const int r0 = lr << 2, c0 = lc << 2;
  const bool dg = (lr == lc);
  const int g = blockIdx.x;
  const int nchunk = 1 << sh;

  // L_m = (eta/NB) * sum of partials
  float t[4][4];
#pragma unroll
  for (int i = 0; i < 4; ++i)
#pragma unroll
    for (int j = 0; j < 4; ++j) t[i][j] = 0.0f;
  for (int p = 0; p < nchunk; ++p) {
    const float* src = ws + WS_PART + (size_t)((g << sh) + p) * MSZ;
#pragma unroll
    for (int i = 0; i < 4; ++i) {
      const float4 v = *(const float4*)(src + ((r0 + i) << 5) + c0);
      t[i][0] += v.x; t[i][1] += v.y; t[i][2] += v.z; t[i][3] += v.w;
    }
  }
  const float scl = 0.01f / 1024.0f;
#pragma unroll
  for (int i = 0; i < 4; ++i)
#pragma unroll
    for (int j = 0; j < 4; ++j) t[i][j] *= scl;
  twrite(Lm, r0, c0, t);

  float ss = 0.0f;
#pragma unroll
  for (int i = 0; i < 4; ++i)
#pragma unroll
    for (int j = 0; j < 4; ++j) ss += t[i][j] * t[i][j];
  ss = wsum(ss);
  const float innrm = 1.0f / fmaxf(sqrtf(ss), 1e-30f);
  float st[4][4];
#pragma unroll
  for (int i = 0; i < 4; ++i)
#pragma unroll
    for (int j = 0; j < 4; ++j) st[i][j] = t[i][j] * innrm;
  twrite(Ss, r0, c0, st);

  float acc[4][4];

  // Newton-Schulz sign iterations: S <- 1.5 S - 0.5 S^3
  for (int it = 0; it < 28; ++it) {
    mm32(Ss, Ss, r0, c0, acc);          // S^2
    wbar();
    twrite(Ts, r0, c0, acc);
    mm32(Ts, Ss, r0, c0, acc);          // S^3
#pragma unroll
    for (int i = 0; i < 4; ++i)
#pragma unroll
      for (int j = 0; j < 4; ++j) st[i][j] = 1.5f * st[i][j] - 0.5f * acc[i][j];
    wbar();
    twrite(Ss, r0, c0, st);
  }

  // B = K * Lm -> Ts (bt in registers)
  float bt[4][4];
  mm32(Ss, Lm, r0, c0, acc);
#pragma unroll
  for (int i = 0; i < 4; ++i)
#pragma unroll
    for (int j = 0; j < 4; ++j) bt[i][j] = acc[i][j];
  wbar();
  twrite(Ts, r0, c0, bt);

  // E2 = B*B -> Us ; inner = 0.5I + B/6 + E2/24 -> Wsl
  mm32(Ts, Ts, r0, c0, acc);
  twrite(Us, r0, c0, acc);
  {
    float in4[4][4];
#pragma unroll
    for (int i = 0; i < 4; ++i)
#pragma unroll
      for (int j = 0; j < 4; ++j) {
        float v = bt[i][j] * (1.0f / 6.0f) + acc[i][j] * (1.0f / 24.0f);
        if (dg && i == j) v += 0.5f;
        in4[i][j] = v;
      }
    twrite(Wsl, r0, c0, in4);
  }

  // poly = I + B + E2*inner -> Us
  mm32(Us, Wsl, r0, c0, acc);
  {
    float pl[4][4];
#pragma unroll
    for (int i = 0; i < 4; ++i)
#pragma unroll
      for (int j = 0; j < 4; ++j) {
        float v = bt[i][j] + acc[i][j];
        if (dg && i == j) v += 1.0f;
        pl[i][j] = v;
      }
    wbar();
    twrite(Us, r0, c0, pl);
  }

  // E = K * poly -> Wsl
  mm32(Ss, Us, r0, c0, acc);
  wbar();
  twrite(Wsl, r0, c0, acc);

  // Cp05 -> Ts
  g2l_mat(Ts, ws + WS_CP05 + (size_t)g * MSZ, lane);

  // Z = E * Cp05 -> Us
  mm32(Wsl, Ts, r0, c0, acc);
  wbar();
  twrite(Us, r0, c0, acc);

  // C_new = Cp05 * Z -> out
  mm32(Ts, Us, r0, c0, acc);
  {
    float* dst = out + (size_t)g * MSZ;
#pragma unroll
    for (int i = 0; i < 4; ++i) {
      float4 v4;
      v4.x = acc[i][0]; v4.y = acc[i][1]; v4.z = acc[i][2]; v4.w = acc[i][3];
      *(float4*)(dst + ((r0 + i) << 5) + c0) = v4;
    }
  }
}

extern "C" void kernel_launch(void* const* d_in, const int* in_sizes, int n_in,
                              void* d_out, int out_size, void* d_ws, size_t ws_size,
                              hipStream_t stream) {
  (void)in_sizes; (void)n_in; (void)out_size;
  const float* X = (const float*)d_in[0];
  const float* C = (const float*)d_in[1];
  const int* idx = (const int*)d_in[2];
  float* out = (float*)d_out;
  float* ws = (float*)d_ws;

  // sh=6: 2048 WGs (16 jobs each) -> 8 WG/CU resident. Fall back to sh=5
  // (1024 WGs) if the workspace can't hold 2048 partial matrices.
  const size_t need6 = (size_t)(WS_PART + (NGRP << 6) * MSZ) * sizeof(float);
  const int sh = (ws_size >= need6) ? 6 : 5;
  const int nwgb = NGRP << sh;

  hipLaunchKernelGGL(centroid_stage_a, dim3(NGRP), dim3(64), 0, stream, C, ws);
  hipLaunchKernelGGL(centroid_stage_b, dim3(nwgb), dim3(64), 0, stream, X, idx, ws,
                     ws + WS_PART, sh);
  hipLaunchKernelGGL(centroid_stage_c, dim3(NGRP), dim3(64), 0, stream, ws, out, sh);
}

// Round 5
// 709.028 us; speedup vs baseline: 1.5586x; 1.5586x over previous
//
// CentroidLayer (Karcher-flow centroid update) — MI355X implementation.
//
// R5: stage_b rewritten on MFMA (v_mfma_f32_32x32x16_bf16) with 3-term bf16
// splits (hi*hi + hi*lo + lo*hi; dropped lo*lo ~2^-16) — error into the output
// is x eta/sqrt(1024) ~ 1e-7. Core trick: the VERIFIED 32x32 C/D layout
// (row=(reg&3)+8*(reg>>2)+4*(lane>>5), col=lane&31) is reg-for-reg the
// B-operand k-pattern of 32x32x16 (k = 4h+(e&3)+8*(e>>2), K-halves = regs
// 0-7 / 8-15), and all operand matrices here are symmetric, so the same
// registers serve as the A-operand via transpose-through-symmetry:
// NO cross-lane data movement, NO LDS in the matmul chain. Only T2..T5 are
// stored in LDS (f32, elementwise reuse for H builds), pad-80B/lane
// (conflict-free b128). Previous fp32-VALU scheme was structurally
// LDS-BW-bound (1 B/FLOP vs 0.5 B/FLOP LDS ceiling -> VALUBusy<=50%).
// stage_c: Newton-Schulz iters 28->20 (lambda_hat ~ 1/sqrt(32) -> converged
// by ~10 iters; 20 = 2x margin). stage_a unchanged (proven).
//
// Algorithm (unchanged from R2/R4, both PASSED absmax 6.1e-5):
//  - stage_a: per group: C^{-1/2}, C^{+1/2} via Chebyshev/Clenshaw on
//    [0.45, ||C||inf*1.02]; aC[g] = 0.48/||C||inf (eig(M) lower bound).
//  - stage_b: 32768 jobs: M = Cm05*X*Cm05; log(M) as degree-29 Chebyshev
//    series (closed-form coeffs, Paterson-Stockmeyer 6x5 folding,
//    14 matmuls/job); deterministic per-wave partial sums.
//  - stage_c: L_m = eta*mean; K = sign(L_m) via Newton-Schulz;
//    E = K*expm(K*L_m); C_new = Cp05*E*Cp05.

#include <hip/hip_runtime.h>
#include <math.h>

#define DEV static __device__ __forceinline__

namespace {

typedef unsigned int  uint;
typedef unsigned short ushort;

constexpr int    MSZ   = 1024;           // 32*32
constexpr int    NGRP  = 32;             // CLS*N
constexpr int    NB    = 1024;           // sampled batch count
constexpr int    XROW  = NGRP * MSZ;     // floats per batch row of X

// ws layout (float offsets)
constexpr size_t WS_CM05 = 0;                      // [32][1024]
constexpr size_t WS_CP05 = WS_CM05 + NGRP * MSZ;   // [32][1024]
constexpr size_t WS_AC   = WS_CP05 + NGRP * MSZ;   // [32]
constexpr size_t WS_PART = 131072;                 // [nwaves][1024]

typedef __attribute__((ext_vector_type(8)))  short bf8v;    // 8 bf16
typedef __attribute__((ext_vector_type(16))) float f32x16;  // 32x32 C/D frag

DEV void wbar() { __builtin_amdgcn_wave_barrier(); }

DEV ushort f2bf_hi(float x) {  // truncate: residual is Sterbenz-exact
  return (ushort)(__float_as_uint(x) >> 16);
}
DEV ushort f2bf_rn(float x) {  // RNE
  uint u = __float_as_uint(x);
  return (ushort)((u + 0x7fffu + ((u >> 16) & 1u)) >> 16);
}
DEV float bf2f(ushort s) { return __uint_as_float(((uint)s) << 16); }
DEV float bf2f_s(short s) { return __uint_as_float(((uint)(ushort)s) << 16); }

struct Split { bf8v h0, h1, l0, l1; };  // K-half 0/1, hi/lo

DEV f32x16 mfma(bf8v a, bf8v b, f32x16 c) {
  return __builtin_amdgcn_mfma_f32_32x32x16_bf16(a, b, c, 0, 0, 0);
}

DEV f32x16 zero16() {
  f32x16 z;
#pragma unroll
  for (int i = 0; i < 16; ++i) z[i] = 0.0f;
  return z;
}

DEV void split16(const float* m, Split& s) {
#pragma unroll
  for (int r = 0; r < 8; ++r) {
    ushort hb = f2bf_hi(m[r]);
    s.h0[r] = (short)hb;
    s.l0[r] = (short)f2bf_rn(m[r] - bf2f(hb));
  }
#pragma unroll
  for (int r = 0; r < 8; ++r) {
    ushort hb = f2bf_hi(m[8 + r]);
    s.h1[r] = (short)hb;
    s.l1[r] = (short)f2bf_rn(m[8 + r] - bf2f(hb));
  }
}

DEV void recon16(const Split& s, float* m) {
#pragma unroll
  for (int r = 0; r < 8; ++r) {
    m[r]     = bf2f_s(s.h0[r]) + bf2f_s(s.l0[r]);
    m[8 + r] = bf2f_s(s.h1[r]) + bf2f_s(s.l1[r]);
  }
}

// P*Q (both symmetric, both as Splits in cmreg form), 3-term bf16 product.
// A-operand = P's regs via transpose-through-symmetry; B-operand = Q's regs.
DEV f32x16 prod(const Split& A, const Split& B, f32x16 acc) {
  acc = mfma(A.h0, B.h0, acc);  acc = mfma(A.h1, B.h1, acc);
  acc = mfma(A.l0, B.h0, acc);  acc = mfma(A.l1, B.h1, acc);
  acc = mfma(A.h0, B.l0, acc);  acc = mfma(A.h1, B.l1, acc);
  return acc;
}

// ---- fp32 helpers for stage_a / stage_c (unchanged micro-kernel) ----
DEV void mm32(const float* __restrict__ A, const float* __restrict__ B,
              int r0, int c0, float acc[4][4]) {
  wbar();
#pragma unroll
  for (int i = 0; i < 4; ++i)
#pragma unroll
    for (int j = 0; j < 4; ++j) acc[i][j] = 0.0f;
#pragma unroll 8
  for (int k = 0; k < 32; ++k) {
    const float4 av = *(const float4*)(A + (k << 5) + r0);
    const float4 bv = *(const float4*)(B + (k << 5) + c0);
    const float a[4] = {av.x, av.y, av.z, av.w};
    const float b[4] = {bv.x, bv.y, bv.z, bv.w};
#pragma unroll
    for (int i = 0; i < 4; ++i)
#pragma unroll
      for (int j = 0; j < 4; ++j) acc[i][j] = fmaf(a[i], b[j], acc[i][j]);
  }
}

DEV void twrite(float* D, int r0, int c0, const float t[4][4]) {
#pragma unroll
  for (int i = 0; i < 4; ++i) {
    float4 v;
    v.x = t[i][0]; v.y = t[i][1]; v.z = t[i][2]; v.w = t[i][3];
    *(float4*)(D + ((r0 + i) << 5) + c0) = v;
  }
}

DEV void tread(const float* M, int r0, int c0, float t[4][4]) {
  wbar();
#pragma unroll
  for (int i = 0; i < 4; ++i) {
    const float4 v = *(const float4*)(M + ((r0 + i) << 5) + c0);
    t[i][0] = v.x; t[i][1] = v.y; t[i][2] = v.z; t[i][3] = v.w;
  }
}

DEV float wsum(float v) {
#pragma unroll
  for (int m = 1; m < 64; m <<= 1) v += __shfl_xor(v, m);
  return v;
}

DEV void g2l_mat(float* dst, const float* src, int lane) {
#pragma unroll
  for (int q = 0; q < 4; ++q) {
    const int off = q * 256 + lane * 4;
    *(float4*)(dst + off) = *(const float4*)(src + off);
  }
  wbar();
}

}  // namespace

// ---------------------------------------------------------------------------
// stage_a: per-group C^{-1/2}, C^{+1/2}, and eig(M) lower bound aC.
// (unchanged from R4 — PASSED)
// ---------------------------------------------------------------------------
__global__ void __launch_bounds__(64, 1)
centroid_stage_a(const float* __restrict__ Cin, float* __restrict__ ws) {
  __shared__ float lds[4 * MSZ];
  __shared__ float coefs[2][21];
  float* CM = lds;
  float* TT = lds + MSZ;
  float* B1 = lds + 2 * MSZ;
  float* B2 = lds + 3 * MSZ;

  const int lane = threadIdx.x;
  const int lr = lane >> 3, lc = lane & 7;
  const int r0 = lr << 2, c0 = lc << 2;
  const bool dg = (lr == lc);
  const int g = blockIdx.x;

  g2l_mat(CM, Cin + (size_t)g * MSZ, lane);

  float tC[4][4];
  tread(CM, r0, c0, tC);
  float rs[4];
#pragma unroll
  for (int i = 0; i < 4; ++i)
    rs[i] = fabsf(tC[i][0]) + fabsf(tC[i][1]) + fabsf(tC[i][2]) + fabsf(tC[i][3]);
#pragma unroll
  for (int m = 1; m < 8; m <<= 1) {
#pragma unroll
    for (int i = 0; i < 4; ++i) rs[i] += __shfl_xor(rs[i], m);
  }
  float mx = fmaxf(fmaxf(rs[0], rs[1]), fmaxf(rs[2], rs[3]));
#pragma unroll
  for (int m = 8; m < 64; m <<= 1) mx = fmaxf(mx, __shfl_xor(mx, m));

  const float aR = 0.45f;
  const float bR = mx * 1.02f;
  const float alpha = 0.5f * (aR + bR), beta = 0.5f * (bR - aR);

  if (lane == 0) ws[WS_AC + g] = 0.48f / bR;

  const float theta = ((float)lane + 0.5f) * (3.14159265358979323846f / 64.0f);
  const float xn = alpha + beta * cosf(theta);
  const float sq = sqrtf(xn);
  const float f1 = 1.0f / (sq + 1e-9f);
  const float f2 = sq;
  for (int k = 0; k <= 20; ++k) {
    const float ck = cosf((float)k * theta);
    const float s1 = wsum(f1 * ck);
    const float s2 = wsum(f2 * ck);
    if (lane == 0) {
      const float sc = (k == 0) ? (1.0f / 64.0f) : (2.0f / 64.0f);
      coefs[0][k] = s1 * sc;
      coefs[1][k] = s2 * sc;
    }
  }
  wbar();

  {
    const float invb = 1.0f / beta;
    float t[4][4];
#pragma unroll
    for (int i = 0; i < 4; ++i)
#pragma unroll
      for (int j = 0; j < 4; ++j) {
        float v = tC[i][j];
        if (dg && i == j) v -= alpha;
        t[i][j] = v * invb;
      }
    twrite(TT, r0, c0, t);
  }

  for (int f = 0; f < 2; ++f) {
    const float* cf = coefs[f];
    {
      float tI[4][4], tZ[4][4];
#pragma unroll
      for (int i = 0; i < 4; ++i)
#pragma unroll
        for (int j = 0; j < 4; ++j) {
          tI[i][j] = (dg && i == j) ? cf[20] : 0.0f;
          tZ[i][j] = 0.0f;
        }
      twrite(B1, r0, c0, tI);
      twrite(B2, r0, c0, tZ);
    }
    float* cur = B1;
    float* prev = B2;
    for (int k = 19; k >= 1; --k) {
      float acc[4][4];
      mm32(TT, cur, r0, c0, acc);
      const float ck = cf[k];
      float pt[4][4];
      tread(prev, r0, c0, pt);
      float nt[4][4];
#pragma unroll
      for (int i = 0; i < 4; ++i)
#pragma unroll
        for (int j = 0; j < 4; ++j) {
          float v = 2.0f * acc[i][j] - pt[i][j];
          if (dg && i == j) v += ck;
          nt[i][j] = v;
        }
      wbar();
      twrite(prev, r0, c0, nt);
      float* tmp = cur; cur = prev; prev = tmp;
    }
    float acc[4][4];
    mm32(TT, cur, r0, c0, acc);
    float pt[4][4];
    tread(prev, r0, c0, pt);
    float* dst = ws + ((f == 0) ? WS_CM05 : WS_CP05) + (size_t)g * MSZ;
#pragma unroll
    for (int i = 0; i < 4; ++i) {
      float4 v4;
      float vv[4];
#pragma unroll
      for (int j = 0; j < 4; ++j) {
        float v = acc[i][j] - pt[i][j];
        if (dg && i == j) v += cf[0];
        vv[j] = v;
      }
      v4.x = vv[0]; v4.y = vv[1]; v4.z = vv[2]; v4.w = vv[3];
      *(float4*)(dst + ((r0 + i) << 5) + c0) = v4;
    }
    wbar();
  }
}

// ---------------------------------------------------------------------------
// stage_b (MFMA): (32<<sh) waves, 2 waves/WG; each wave: NB>>sh jobs.
// cmreg convention: lane holds col=lane&31 of rows RR(r,h)=(r&3)+8*(r>>2)+4h
// (h=lane>>5) — simultaneously the verified 32x32 MFMA C/D layout AND (for
// symmetric matrices) the A/B operand layout of 32x32x16 (regs 0-7 = K-half
// 0, regs 8-15 = K-half 1).
// LDS: per wave, T2..T5 as f32 (elementwise reuse in H builds);
// 80 B/lane stride (conflict-free for b128: 8 lanes cover all 32 banks).
// ---------------------------------------------------------------------------
__global__ void __launch_bounds__(128, 2)
centroid_stage_b(const float* __restrict__ X, const int* __restrict__ idx,
                 const float* __restrict__ ws, float* __restrict__ partials,
                 int sh) {
  __shared__ float lds[2 * 4 * 1280];  // 2 waves x 4 mats x (64 lanes x 20 fl)

  const int tid  = threadIdx.x;
  const int wv   = tid >> 6;
  const int lane = tid & 63;
  const int col  = lane & 31;
  const int h    = lane >> 5;

  const int w    = blockIdx.x * 2 + wv;   // global wave id
  const int g    = w >> sh;
  const int njpw = NB >> sh;
  const int b0   = (w & ((1 << sh) - 1)) * njpw;

  float* lw = lds + wv * 5120 + lane * 20;  // + mat*1280 + frag*4

  // diagonal ownership: element (row==col) lives at reg rd iff hasd
  const bool hasd = ((col >> 2) & 1) == h;
  const int  rd   = (col & 3) + 4 * (col >> 3);

  // Cm05 -> cmreg -> split (WG-persistent)
  float tf[16];
  {
    const float* cb = ws + WS_CM05 + (size_t)g * MSZ + 128 * h + col;
#pragma unroll
    for (int r = 0; r < 16; ++r) tf[r] = cb[(((r & 3) + 8 * (r >> 2)) << 5)];
  }
  Split CmS; split16(tf, CmS);
  const float aB = ws[WS_AC + g];

  f32x16 Sacc = zero16();

  // prefetch first X tile into registers (cmreg gather: 2 coalesced 128B
  // segments per element-row)
  float xc[16];
  {
    const int bi = idx[b0];
    const float* xb = X + (size_t)bi * XROW + (size_t)g * MSZ + 128 * h + col;
#pragma unroll
    for (int r = 0; r < 16; ++r) xc[r] = xb[(((r & 3) + 8 * (r >> 2)) << 5)];
  }

  for (int jb = 0; jb < njpw; ++jb) {
    Split XS; split16(xc, XS);
    {  // prefetch next job's X (consumed next iteration)
      const int jn = (jb + 1 < njpw) ? jb + 1 : jb;
      const int bi = idx[b0 + jn];
      const float* xb = X + (size_t)bi * XROW + (size_t)g * MSZ + 128 * h + col;
#pragma unroll
      for (int r = 0; r < 16; ++r) xc[r] = xb[(((r & 3) + 8 * (r >> 2)) << 5)];
    }

    // V = X * Cm05 (A=X exactly symmetric); M = Cm05 * V (A=Cm05 symmetric)
    f32x16 acc = prod(XS, CmS, zero16());
#pragma unroll
    for (int r = 0; r < 16; ++r) tf[r] = acc[r];
    Split VS; split16(tf, VS);
    acc = prod(CmS, VS, zero16());

    // bB = ||M||_1 (= ||M||_inf for symmetric M): column sums then max
    float s1 = 0.0f;
#pragma unroll
    for (int r = 0; r < 16; ++r) s1 += fabsf(acc[r]);
    s1 += __shfl_xor(s1, 32);
    s1 = fmaxf(s1, __shfl_xor(s1, 16));
    s1 = fmaxf(s1, __shfl_xor(s1, 8));
    s1 = fmaxf(s1, __shfl_xor(s1, 4));
    s1 = fmaxf(s1, __shfl_xor(s1, 2));
    s1 = fmaxf(s1, __shfl_xor(s1, 1));
    const float bB = s1 * 1.001f + 1e-6f;

    const float alpha = 0.5f * (aB + bB);
    const float beta  = 0.5f * (bB - aB);
    const float wq = beta / alpha;
    const float zq = wq / (1.0f + sqrtf(fmaxf(1.0f - wq * wq, 0.0f)));

    float cp[30];
    cp[0] = logf(alpha) - log1pf(zq * zq);
    {
      const float tz = -zq;
      float tp = tz;
#pragma unroll
      for (int k = 1; k < 30; ++k) {
        cp[k] = -2.0f * tp * (1.0f / (float)k);
        tp *= tz;
      }
    }
#pragma unroll
    for (int j = 4; j >= 1; --j)
#pragma unroll
      for (int i = 1; i <= 5; ++i) cp[6 * j - i] -= cp[6 * j + i];

    const float invb = 1.0f / beta;

    // T1 = (M - alpha I)/beta ; S += cp0*I + cp1*T1
    float t1f[16];
#pragma unroll
    for (int r = 0; r < 16; ++r) {
      float v = acc[r];
      if (hasd && r == rd) v -= alpha;
      v *= invb;
      t1f[r] = v;
      Sacc[r] += cp[1] * v;
      if (hasd && r == rd) Sacc[r] += cp[0];
    }
    Split T1S; split16(t1f, T1S);

    Split curS, prevS;
    float prec[16];

    // T2 = 2 T1*T1 - I  -> LDS mat 0
    acc = prod(T1S, T1S, zero16());
    wbar();
#pragma unroll
    for (int r = 0; r < 16; ++r) {
      float v = 2.0f * acc[r] - ((hasd && r == rd) ? 1.0f : 0.0f);
      tf[r] = v; Sacc[r] += cp[2] * v;
    }
#pragma unroll
    for (int f = 0; f < 4; ++f) {
      float4 v4; v4.x = tf[4*f]; v4.y = tf[4*f+1]; v4.z = tf[4*f+2]; v4.w = tf[4*f+3];
      *(float4*)(lw + 0 * 1280 + f * 4) = v4;
    }
    split16(tf, curS);
    prevS = T1S;

    // T3 = 2 T1*T2 - T1 -> LDS 1
    acc = prod(T1S, curS, zero16());
#pragma unroll
    for (int r = 0; r < 16; ++r) {
      float v = 2.0f * acc[r] - t1f[r];
      tf[r] = v; Sacc[r] += cp[3] * v;
    }
#pragma unroll
    for (int f = 0; f < 4; ++f) {
      float4 v4; v4.x = tf[4*f]; v4.y = tf[4*f+1]; v4.z = tf[4*f+2]; v4.w = tf[4*f+3];
      *(float4*)(lw + 1 * 1280 + f * 4) = v4;
    }
    prevS = curS; split16(tf, curS);

    // T4 = 2 T1*T3 - T2 -> LDS 2
    acc = prod(T1S, curS, zero16());
    recon16(prevS, prec);   // T2
#pragma unroll
    for (int r = 0; r < 16; ++r) {
      float v = 2.0f * acc[r] - prec[r];
      tf[r] = v; Sacc[r] += cp[4] * v;
    }
#pragma unroll
    for (int f = 0; f < 4; ++f) {
      float4 v4; v4.x = tf[4*f]; v4.y = tf[4*f+1]; v4.z = tf[4*f+2]; v4.w = tf[4*f+3];
      *(float4*)(lw + 2 * 1280 + f * 4) = v4;
    }
    prevS = curS; split16(tf, curS);

    // T5 = 2 T1*T4 - T3 -> LDS 3
    acc = prod(T1S, curS, zero16());
    recon16(prevS, prec);   // T3
#pragma unroll
    for (int r = 0; r < 16; ++r) {
      float v = 2.0f * acc[r] - prec[r];
      tf[r] = v; Sacc[r] += cp[5] * v;
    }
#pragma unroll
    for (int f = 0; f < 4; ++f) {
      float4 v4; v4.x = tf[4*f]; v4.y = tf[4*f+1]; v4.z = tf[4*f+2]; v4.w = tf[4*f+3];
      *(float4*)(lw + 3 * 1280 + f * 4) = v4;
    }
    prevS = curS; split16(tf, curS);

    // T6 = 2 T1*T5 - T4
    acc = prod(T1S, curS, zero16());
    recon16(prevS, prec);   // T4
    Split T6S;
#pragma unroll
    for (int r = 0; r < 16; ++r) {
      float v = 2.0f * acc[r] - prec[r];
      tf[r] = v; Sacc[r] += cp[6] * v;
    }
    split16(tf, T6S);

    // ---- j = 1..4: H_j = 2*(cp[6j+1]*T1 + sum_m cp[6j+2+m]*T_{m+2});
    //      S += T_{6j} * H_j ; build T_{6(j+1)}
    float hh[16];
    Split HS;

    // j=1
    wbar();
#pragma unroll
    for (int r = 0; r < 16; ++r) hh[r] = cp[7] * t1f[r];
#pragma unroll
    for (int m = 0; m < 4; ++m)
#pragma unroll
      for (int f = 0; f < 4; ++f) {
        const float4 v = *(const float4*)(lw + m * 1280 + f * 4);
        hh[4*f+0] += cp[8+m] * v.x; hh[4*f+1] += cp[8+m] * v.y;
        hh[4*f+2] += cp[8+m] * v.z; hh[4*f+3] += cp[8+m] * v.w;
      }
#pragma unroll
    for (int r = 0; r < 16; ++r) hh[r] *= 2.0f;
    split16(hh, HS);
    Sacc = prod(T6S, HS, Sacc);
    // T12 = 2 T6*T6 - I
    acc = prod(T6S, T6S, zero16());
#pragma unroll
    for (int r = 0; r < 16; ++r) {
      float v = 2.0f * acc[r] - ((hasd && r == rd) ? 1.0f : 0.0f);
      tf[r] = v; Sacc[r] += cp[12] * v;
    }
    split16(tf, curS);          // cur6 = T12

    // j=2
#pragma unroll
    for (int r = 0; r < 16; ++r) hh[r] = cp[13] * t1f[r];
#pragma unroll
    for (int m = 0; m < 4; ++m)
#pragma unroll
      for (int f = 0; f < 4; ++f) {
        const float4 v = *(const float4*)(lw + m * 1280 + f * 4);
        hh[4*f+0] += cp[14+m] * v.x; hh[4*f+1] += cp[14+m] * v.y;
        hh[4*f+2] += cp[14+m] * v.z; hh[4*f+3] += cp[14+m] * v.w;
      }
#pragma unroll
    for (int r = 0; r < 16; ++r) hh[r] *= 2.0f;
    split16(hh, HS);
    Sacc = prod(curS, HS, Sacc);    // A = T12
    // T18 = 2 T6*T12 - T6
    acc = prod(T6S, curS, zero16());
    recon16(T6S, prec);
#pragma unroll
    for (int r = 0; r < 16; ++r) {
      float v = 2.0f * acc[r] - prec[r];
      tf[r] = v; Sacc[r] += cp[18] * v;
    }
    prevS = curS; split16(tf, curS);   // prev6 = T12, cur6 = T18

    // j=3
#pragma unroll
    for (int r = 0; r < 16; ++r) hh[r] = cp[19] * t1f[r];
#pragma unroll
    for (int m = 0; m < 4; ++m)
#pragma unroll
      for (int f = 0; f < 4; ++f) {
        const float4 v = *(const float4*)(lw + m * 1280 + f * 4);
        hh[4*f+0] += cp[20+m] * v.x; hh[4*f+1] += cp[20+m] * v.y;
        hh[4*f+2] += cp[20+m] * v.z; hh[4*f+3] += cp[20+m] * v.w;
      }
#pragma unroll
    for (int r = 0; r < 16; ++r) hh[r] *= 2.0f;
    split16(hh, HS);
    Sacc = prod(curS, HS, Sacc);    // A = T18
    // T24 = 2 T6*T18 - T12
    acc = prod(T6S, curS, zero16());
    recon16(prevS, prec);
#pragma unroll
    for (int r = 0; r < 16; ++r) {
      float v = 2.0f * acc[r] - prec[r];
      tf[r] = v; Sacc[r] += cp[24] * v;
    }
    split16(tf, curS);              // cur6 = T24

    // j=4
#pragma unroll
    for (int r = 0; r < 16; ++r) hh[r] = cp[25] * t1f[r];
#pragma unroll
    for (int m = 0; m < 4; ++m)
#pragma unroll
      for (int f = 0; f < 4; ++f) {
        const float4 v = *(const float4*)(lw + m * 1280 + f * 4);
        hh[4*f+0] += cp[26+m] * v.x; hh[4*f+1] += cp[26+m] * v.y;
        hh[4*f+2] += cp[26+m] * v.z; hh[4*f+3] += cp[26+m] * v.w;
      }
#pragma unroll
    for (int r = 0; r < 16; ++r) hh[r] *= 2.0f;
    split16(hh, HS);
    Sacc = prod(curS, HS, Sacc);    // A = T24
    wbar();
  }

  // partial sum out (row-major, deterministic reduction in stage_c)
  {
    float* dst = partials + (size_t)w * MSZ + 128 * h + col;
#pragma unroll
    for (int r = 0; r < 16; ++r) dst[(((r & 3) + 8 * (r >> 2)) << 5)] = Sacc[r];
  }
}

// ---------------------------------------------------------------------------
// stage_c: per group: L_m; K=sign(L_m) (Newton-Schulz, 20 iters); E=K*exp(KL);
//          C_new = Cp05 * (E * Cp05). Single-wave WG (as R4, PASSED).
// ---------------------------------------------------------------------------
__global__ void __launch_bounds__(64, 1)
centroid_stage_c(const float* __restrict__ ws, float* __restrict__ out, int sh) {
  __shared__ float lds[5 * MSZ];
  float* Lm = lds;
  float* Ss = lds + MSZ;
  float* Ts = lds + 2 * MSZ;
  float* Us = lds + 3 * MSZ;
  float* Wsl = lds + 4 * MSZ;

  const int lane = threadIdx.x;
  const int lr = lane >> 3, lc = lane & 7;
  const int r0 = lr << 2, c0 = lc << 2;
  const bool dg = (lr == lc);
  const int g = blockIdx.x;
  const int nchunk = 1 << sh;

  float t[4][4];
#pragma unroll
  for (int i = 0; i < 4; ++i)
#pragma unroll
    for (int j = 0; j < 4; ++j) t[i][j] = 0.0f;
  for (int p = 0; p < nchunk; ++p) {
    const float* src = ws + WS_PART + (size_t)((g << sh) + p) * MSZ;
#pragma unroll
    for (int i = 0; i < 4; ++i) {
      const float4 v = *(const float4*)(src + ((r0 + i) << 5) + c0);
      t[i][0] += v.x; t[i][1] += v.y; t[i][2] += v.z; t[i][3] += v.w;
    }
  }
  const float scl = 0.01f / 1024.0f;
#pragma unroll
  for (int i = 0; i < 4; ++i)
#pragma unroll
    for (int j = 0; j < 4; ++j) t[i][j] *= scl;
  twrite(Lm, r0, c0, t);

  float ss = 0.0f;
#pragma unroll
  for (int i = 0; i < 4; ++i)
#pragma unroll
    for (int j = 0; j < 4; ++j) ss += t[i][j] * t[i][j];
  ss = wsum(ss);
  const float innrm = 1.0f / fmaxf(sqrtf(ss), 1e-30f);
  float st[4][4];
#pragma unroll
  for (int i = 0; i < 4; ++i)
#pragma unroll
    for (int j = 0; j < 4; ++j) st[i][j] = t[i][j] * innrm;
  twrite(Ss, r0, c0, st);

  float acc[4][4];

  for (int it = 0; it < 20; ++it) {
    mm32(Ss, Ss, r0, c0, acc);
    wbar();
    twrite(Ts, r0, c0, acc);
    mm32(Ts, Ss, r0, c0, acc);
#pragma unroll
    for (int i = 0; i < 4; ++i)
#pragma unroll
      for (int j = 0; j < 4; ++j) st[i][j] = 1.5f * st[i][j] - 0.5f * acc[i][j];
    wbar();
    twrite(Ss, r0, c0, st);
  }

  float bt[4][4];
  mm32(Ss, Lm, r0, c0, acc);
#pragma unroll
  for (int i = 0; i < 4; ++i)
#pragma unroll
    for (int j = 0; j < 4; ++j) bt[i][j] = acc[i][j];
  wbar();
  twrite(Ts, r0, c0, bt);

  mm32(Ts, Ts, r0, c0, acc);
  twrite(Us, r0, c0, acc);
  {
    float in4[4][4];
#pragma unroll
    for (int i = 0; i < 4; ++i)
#pragma unroll
      for (int j = 0; j < 4; ++j) {
        float v = bt[i][j] * (1.0f / 6.0f) + acc[i][j] * (1.0f / 24.0f);
        if (dg && i == j) v += 0.5f;
        in4[i][j] = v;
      }
    twrite(Wsl, r0, c0, in4);
  }

  mm32(Us, Wsl, r0, c0, acc);
  {
    float pl[4][4];
#pragma unroll
    for (int i = 0; i < 4; ++i)
#pragma unroll
      for (int j = 0; j < 4; ++j) {
        float v = bt[i][j] + acc[i][j];
        if (dg && i == j) v += 1.0f;
        pl[i][j] = v;
      }
    wbar();
    twrite(Us, r0, c0, pl);
  }

  mm32(Ss, Us, r0, c0, acc);
  wbar();
  twrite(Wsl, r0, c0, acc);

  g2l_mat(Ts, ws + WS_CP05 + (size_t)g * MSZ, lane);

  mm32(Wsl, Ts, r0, c0, acc);
  wbar();
  twrite(Us, r0, c0, acc);

  mm32(Ts, Us, r0, c0, acc);
  {
    float* dst = out + (size_t)g * MSZ;
#pragma unroll
    for (int i = 0; i < 4; ++i) {
      float4 v4;
      v4.x = acc[i][0]; v4.y = acc[i][1]; v4.z = acc[i][2]; v4.w = acc[i][3];
      *(float4*)(dst + ((r0 + i) << 5) + c0) = v4;
    }
  }
}

extern "C" void kernel_launch(void* const* d_in, const int* in_sizes, int n_in,
                              void* d_out, int out_size, void* d_ws, size_t ws_size,
                              hipStream_t stream) {
  (void)in_sizes; (void)n_in; (void)out_size;
  const float* X = (const float*)d_in[0];
  const float* C = (const float*)d_in[1];
  const int* idx = (const int*)d_in[2];
  float* out = (float*)d_out;
  float* ws = (float*)d_ws;

  // sh=6: 2048 waves (16 jobs each), 2 waves per 128-thread WG.
  const size_t need6 = (size_t)(WS_PART + (NGRP << 6) * MSZ) * sizeof(float);
  const int sh = (ws_size >= need6) ? 6 : 5;
  const int nblk = (NGRP << sh) / 2;

  hipLaunchKernelGGL(centroid_stage_a, dim3(NGRP), dim3(64), 0, stream, C, ws);
  hipLaunchKernelGGL(centroid_stage_b, dim3(nblk), dim3(128), 0, stream, X, idx, ws,
                     ws + WS_PART, sh);
  hipLaunchKernelGGL(centroid_stage_c, dim3(NGRP), dim3(64), 0, stream, ws, out, sh);
}

// Round 6
// 530.217 us; speedup vs baseline: 2.0843x; 1.3372x over previous
//
// CentroidLayer (Karcher-flow centroid update) — MI355X implementation.
//
// R6 (vs R5, which PASSED at 324us stage_b): kill the two measured costs —
// register spills (WRITE_SIZE 153MB of scratch; VGPR capped 128) and split
// overhead (4250 VALU/job vs ~1700 expected):
//  - stage_b: 64-thread blocks, __launch_bounds__(64,2) -> 256-VGPR cap,
//    8 blocks/CU (20KB LDS each = 160KB exactly). T2..T5 live in per-lane-
//    PRIVATE LDS slots (no cross-lane traffic -> no barriers, reads replace
//    the recon16 VALU). cp[]/alpha/invb are wave-uniform -> readfirstlane
//    into SGPRs (frees ~32 VGPRs; VALU reads 1 SGPR for free).
//  - bf16 splits via __float2bfloat16/__bfloat162float intrinsic casts (RNE;
//    hi/lo residual remains exact) so the compiler emits v_cvt_pk_bf16_f32
//    instead of hand-rolled bit-RNE + short-vector packing.
//  - H-only Chebyshev coefficients pre-doubled into cp (drops the *2 pass).
// Verified core (R5 PASS): cmreg layout — lane holds col=lane&31 of rows
// RR(r,h)=(r&3)+8*(r>>2)+4h — is simultaneously the 32x32 MFMA C/D layout
// AND (for symmetric matrices, via transpose-through-symmetry) the A-operand;
// any matrix in cmreg is a valid B-operand. 3-term bf16 split products
// (hi*hi + lo*hi + hi*lo) on v_mfma_f32_32x32x16_bf16.
//
// Algorithm (unchanged; PASSED R2/R4/R5, absmax 6.1e-5):
//  - stage_a: per group: C^{-1/2}, C^{+1/2} via Chebyshev/Clenshaw on
//    [0.45, ||C||inf*1.02]; aC[g] = 0.48/||C||inf (eig(M) lower bound).
//  - stage_b: 32768 jobs: M = Cm05*X*Cm05; log(M) as degree-29 Chebyshev
//    series (closed-form coeffs, Paterson-Stockmeyer 6x5 folding,
//    14 matmul-products/job); deterministic per-wave partial sums.
//  - stage_c: L_m = eta*mean; K = sign(L_m) via 20 Newton-Schulz iters;
//    E = K*expm(K*L_m) (4-term Taylor); C_new = Cp05*E*Cp05.

#include <hip/hip_runtime.h>
#include <hip/hip_bf16.h>
#include <math.h>

#define DEV static __device__ __forceinline__

namespace {

typedef unsigned int uint;

constexpr int    MSZ   = 1024;           // 32*32
constexpr int    NGRP  = 32;             // CLS*N
constexpr int    NB    = 1024;           // sampled batch count
constexpr int    XROW  = NGRP * MSZ;     // floats per batch row of X

// ws layout (float offsets)
constexpr size_t WS_CM05 = 0;                      // [32][1024]
constexpr size_t WS_CP05 = WS_CM05 + NGRP * MSZ;   // [32][1024]
constexpr size_t WS_AC   = WS_CP05 + NGRP * MSZ;   // [32]
constexpr size_t WS_PART = 131072;                 // [nwaves][1024]

typedef __attribute__((ext_vector_type(8)))  short bf8v;    // 8 bf16
typedef __attribute__((ext_vector_type(16))) float f32x16;  // 32x32 C/D frag

DEV void wbar() { __builtin_amdgcn_wave_barrier(); }

DEV float rfl(float x) {  // wave-uniform value -> SGPR
  return __uint_as_float((uint)__builtin_amdgcn_readfirstlane((int)__float_as_uint(x)));
}

struct Split { bf8v h0, h1, l0, l1; };  // K-half 0/1, hi/lo

DEV f32x16 mfma(bf8v a, bf8v b, f32x16 c) {
  return __builtin_amdgcn_mfma_f32_32x32x16_bf16(a, b, c, 0, 0, 0);
}

DEV f32x16 zero16() {
  f32x16 z;
#pragma unroll
  for (int i = 0; i < 16; ++i) z[i] = 0.0f;
  return z;
}

DEV short bfs(float x) {  // RNE via intrinsic cast (compiler -> cvt_pk pairs)
  __hip_bfloat16 h = __float2bfloat16(x);
  short v; __builtin_memcpy(&v, &h, 2); return v;
}
DEV float bff(short s) {
  __hip_bfloat16 h; __builtin_memcpy(&h, &s, 2);
  return __bfloat162float(h);
}

DEV void split16(const float* m, Split& s) {
#pragma unroll
  for (int r = 0; r < 8; ++r) {
    const float x0 = m[r], x1 = m[8 + r];
    const short hA = bfs(x0), hB = bfs(x1);
    s.h0[r] = hA; s.h1[r] = hB;
    s.l0[r] = bfs(x0 - bff(hA));
    s.l1[r] = bfs(x1 - bff(hB));
  }
}

// P*Q in cmreg form: A-operand = P via transpose-through-symmetry (P must be
// symmetric); B-operand = Q (any matrix). 3-term bf16 product.
DEV f32x16 prod(const Split& A, const Split& B, f32x16 acc) {
  acc = mfma(A.h0, B.h0, acc);  acc = mfma(A.h1, B.h1, acc);
  acc = mfma(A.l0, B.h0, acc);  acc = mfma(A.l1, B.h1, acc);
  acc = mfma(A.h0, B.l0, acc);  acc = mfma(A.h1, B.l1, acc);
  return acc;
}

// per-lane-private LDS T-slots (stride 80 B/lane -> 2-way bank alias, free)
DEV void lwrite(float* lw, int mat, const float t[16]) {
#pragma unroll
  for (int f = 0; f < 4; ++f) {
    float4 v;
    v.x = t[4*f]; v.y = t[4*f+1]; v.z = t[4*f+2]; v.w = t[4*f+3];
    *(float4*)(lw + mat * 1280 + f * 4) = v;
  }
}
DEV void lread(const float* lw, int mat, float t[16]) {
#pragma unroll
  for (int f = 0; f < 4; ++f) {
    const float4 v = *(const float4*)(lw + mat * 1280 + f * 4);
    t[4*f] = v.x; t[4*f+1] = v.y; t[4*f+2] = v.z; t[4*f+3] = v.w;
  }
}

DEV void hbuild(const float* lw, const float t1f[16], float c1, float c2,
                float c3, float c4, float c5, float hh[16]) {
#pragma unroll
  for (int r = 0; r < 16; ++r) hh[r] = c1 * t1f[r];
  const float cm[4] = {c2, c3, c4, c5};
#pragma unroll
  for (int m = 0; m < 4; ++m)
#pragma unroll
    for (int f = 0; f < 4; ++f) {
      const float4 v = *(const float4*)(lw + m * 1280 + f * 4);
      hh[4*f+0] += cm[m] * v.x; hh[4*f+1] += cm[m] * v.y;
      hh[4*f+2] += cm[m] * v.z; hh[4*f+3] += cm[m] * v.w;
    }
}

// ---- fp32 helpers for stage_a / stage_c (unchanged, proven) ----
DEV void mm32(const float* __restrict__ A, const float* __restrict__ B,
              int r0, int c0, float acc[4][4]) {
  wbar();
#pragma unroll
  for (int i = 0; i < 4; ++i)
#pragma unroll
    for (int j = 0; j < 4; ++j) acc[i][j] = 0.0f;
#pragma unroll 8
  for (int k = 0; k < 32; ++k) {
    const float4 av = *(const float4*)(A + (k << 5) + r0);
    const float4 bv = *(const float4*)(B + (k << 5) + c0);
    const float a[4] = {av.x, av.y, av.z, av.w};
    const float b[4] = {bv.x, bv.y, bv.z, bv.w};
#pragma unroll
    for (int i = 0; i < 4; ++i)
#pragma unroll
      for (int j = 0; j < 4; ++j) acc[i][j] = fmaf(a[i], b[j], acc[i][j]);
  }
}

DEV void twrite(float* D, int r0, int c0, const float t[4][4]) {
#pragma unroll
  for (int i = 0; i < 4; ++i) {
    float4 v;
    v.x = t[i][0]; v.y = t[i][1]; v.z = t[i][2]; v.w = t[i][3];
    *(float4*)(D + ((r0 + i) << 5) + c0) = v;
  }
}

DEV void tread(const float* M, int r0, int c0, float t[4][4]) {
  wbar();
#pragma unroll
  for (int i = 0; i < 4; ++i) {
    const float4 v = *(const float4*)(M + ((r0 + i) << 5) + c0);
    t[i][0] = v.x; t[i][1] = v.y; t[i][2] = v.z; t[i][3] = v.w;
  }
}

DEV float wsum(float v) {
#pragma unroll
  for (int m = 1; m < 64; m <<= 1) v += __shfl_xor(v, m);
  return v;
}

DEV void g2l_mat(float* dst, const float* src, int lane) {
#pragma unroll
  for (int q = 0; q < 4; ++q) {
    const int off = q * 256 + lane * 4;
    *(float4*)(dst + off) = *(const float4*)(src + off);
  }
  wbar();
}

}  // namespace

// ---------------------------------------------------------------------------
// stage_a: per-group C^{-1/2}, C^{+1/2}, and eig(M) lower bound aC.
// (unchanged from R5 — PASSED)
// ---------------------------------------------------------------------------
__global__ void __launch_bounds__(64, 1)
centroid_stage_a(const float* __restrict__ Cin, float* __restrict__ ws) {
  __shared__ float lds[4 * MSZ];
  __shared__ float coefs[2][21];
  float* CM = lds;
  float* TT = lds + MSZ;
  float* B1 = lds + 2 * MSZ;
  float* B2 = lds + 3 * MSZ;

  const int lane = threadIdx.x;
  const int lr = lane >> 3, lc = lane & 7;
  const int r0 = lr << 2, c0 = lc << 2;
  const bool dg = (lr == lc);
  const int g = blockIdx.x;

  g2l_mat(CM, Cin + (size_t)g * MSZ, lane);

  float tC[4][4];
  tread(CM, r0, c0, tC);
  float rs[4];
#pragma unroll
  for (int i = 0; i < 4; ++i)
    rs[i] = fabsf(tC[i][0]) + fabsf(tC[i][1]) + fabsf(tC[i][2]) + fabsf(tC[i][3]);
#pragma unroll
  for (int m = 1; m < 8; m <<= 1) {
#pragma unroll
    for (int i = 0; i < 4; ++i) rs[i] += __shfl_xor(rs[i], m);
  }
  float mx = fmaxf(fmaxf(rs[0], rs[1]), fmaxf(rs[2], rs[3]));
#pragma unroll
  for (int m = 8; m < 64; m <<= 1) mx = fmaxf(mx, __shfl_xor(mx, m));

  const float aR = 0.45f;
  const float bR = mx * 1.02f;
  const float alpha = 0.5f * (aR + bR), beta = 0.5f * (bR - aR);

  if (lane == 0) ws[WS_AC + g] = 0.48f / bR;

  const float theta = ((float)lane + 0.5f) * (3.14159265358979323846f / 64.0f);
  const float xn = alpha + beta * cosf(theta);
  const float sq = sqrtf(xn);
  const float f1 = 1.0f / (sq + 1e-9f);
  const float f2 = sq;
  for (int k = 0; k <= 20; ++k) {
    const float ck = cosf((float)k * theta);
    const float s1 = wsum(f1 * ck);
    const float s2 = wsum(f2 * ck);
    if (lane == 0) {
      const float sc = (k == 0) ? (1.0f / 64.0f) : (2.0f / 64.0f);
      coefs[0][k] = s1 * sc;
      coefs[1][k] = s2 * sc;
    }
  }
  wbar();

  {
    const float invb = 1.0f / beta;
    float t[4][4];
#pragma unroll
    for (int i = 0; i < 4; ++i)
#pragma unroll
      for (int j = 0; j < 4; ++j) {
        float v = tC[i][j];
        if (dg && i == j) v -= alpha;
        t[i][j] = v * invb;
      }
    twrite(TT, r0, c0, t);
  }

  for (int f = 0; f < 2; ++f) {
    const float* cf = coefs[f];
    {
      float tI[4][4], tZ[4][4];
#pragma unroll
      for (int i = 0; i < 4; ++i)
#pragma unroll
        for (int j = 0; j < 4; ++j) {
          tI[i][j] = (dg && i == j) ? cf[20] : 0.0f;
          tZ[i][j] = 0.0f;
        }
      twrite(B1, r0, c0, tI);
      twrite(B2, r0, c0, tZ);
    }
    float* cur = B1;
    float* prev = B2;
    for (int k = 19; k >= 1; --k) {
      float acc[4][4];
      mm32(TT, cur, r0, c0, acc);
      const float ck = cf[k];
      float pt[4][4];
      tread(prev, r0, c0, pt);
      float nt[4][4];
#pragma unroll
      for (int i = 0; i < 4; ++i)
#pragma unroll
        for (int j = 0; j < 4; ++j) {
          float v = 2.0f * acc[i][j] - pt[i][j];
          if (dg && i == j) v += ck;
          nt[i][j] = v;
        }
      wbar();
      twrite(prev, r0, c0, nt);
      float* tmp = cur; cur = prev; prev = tmp;
    }
    float acc[4][4];
    mm32(TT, cur, r0, c0, acc);
    float pt[4][4];
    tread(prev, r0, c0, pt);
    float* dst = ws + ((f == 0) ? WS_CM05 : WS_CP05) + (size_t)g * MSZ;
#pragma unroll
    for (int i = 0; i < 4; ++i) {
      float4 v4;
      float vv[4];
#pragma unroll
      for (int j = 0; j < 4; ++j) {
        float v = acc[i][j] - pt[i][j];
        if (dg && i == j) v += cf[0];
        vv[j] = v;
      }
      v4.x = vv[0]; v4.y = vv[1]; v4.z = vv[2]; v4.w = vv[3];
      *(float4*)(dst + ((r0 + i) << 5) + c0) = v4;
    }
    wbar();
  }
}

// ---------------------------------------------------------------------------
// stage_b (MFMA): (32<<sh) single-wave blocks; each: NB>>sh jobs.
// __launch_bounds__(64,2): 256-VGPR cap, 8 blocks/CU (LDS 20KB = 160KB/CU).
// ---------------------------------------------------------------------------
__global__ void __launch_bounds__(64, 2)
centroid_stage_b(const float* __restrict__ X, const int* __restrict__ idx,
                 const float* __restrict__ ws, float* __restrict__ partials,
                 int sh) {
  __shared__ float lds[4 * 1280];  // 4 per-lane-private T-slots (T2..T5)

  const int lane = threadIdx.x;
  const int col  = lane & 31;
  const int h    = lane >> 5;

  const int w    = blockIdx.x;
  const int g    = w >> sh;
  const int njpw = NB >> sh;
  const int b0   = (w & ((1 << sh) - 1)) * njpw;

  float* lw = lds + lane * 20;

  const bool hasd = ((col >> 2) & 1) == h;
  const int  rd   = (col & 3) + 4 * (col >> 3);

  float tf[16];
  {
    const float* cb = ws + WS_CM05 + (size_t)g * MSZ + 128 * h + col;
#pragma unroll
    for (int r = 0; r < 16; ++r) tf[r] = cb[(((r & 3) + 8 * (r >> 2)) << 5)];
  }
  Split CmS; split16(tf, CmS);
  const float aB = ws[WS_AC + g];

  f32x16 Sacc = zero16();

  float xc[16];
  {
    const int bi = idx[b0];
    const float* xb = X + (size_t)bi * XROW + (size_t)g * MSZ + 128 * h + col;
#pragma unroll
    for (int r = 0; r < 16; ++r) xc[r] = xb[(((r & 3) + 8 * (r >> 2)) << 5)];
  }

  for (int jb = 0; jb < njpw; ++jb) {
    Split XS; split16(xc, XS);
    {  // prefetch next job's X (hidden under this job's compute)
      const int jn = (jb + 1 < njpw) ? jb + 1 : jb;
      const int bi = idx[b0 + jn];
      const float* xb = X + (size_t)bi * XROW + (size_t)g * MSZ + 128 * h + col;
#pragma unroll
      for (int r = 0; r < 16; ++r) xc[r] = xb[(((r & 3) + 8 * (r >> 2)) << 5)];
    }

    // V = X * Cm05 (A=X symmetric); M = Cm05 * V (A=Cm05 symmetric, B=V any)
    f32x16 acc = prod(XS, CmS, zero16());
#pragma unroll
    for (int r = 0; r < 16; ++r) tf[r] = acc[r];
    Split VS; split16(tf, VS);
    acc = prod(CmS, VS, zero16());

    // bB = ||M||_1 (= ||M||_inf, symmetric): column sums then max
    float s1 = 0.0f;
#pragma unroll
    for (int r = 0; r < 16; ++r) s1 += fabsf(acc[r]);
    s1 += __shfl_xor(s1, 32);
    s1 = fmaxf(s1, __shfl_xor(s1, 16));
    s1 = fmaxf(s1, __shfl_xor(s1, 8));
    s1 = fmaxf(s1, __shfl_xor(s1, 4));
    s1 = fmaxf(s1, __shfl_xor(s1, 2));
    s1 = fmaxf(s1, __shfl_xor(s1, 1));
    const float bB = rfl(s1 * 1.001f + 1e-6f);

    const float alpha = rfl(0.5f * (aB + bB));
    const float beta  = 0.5f * (bB - aB);
    const float wq = beta / alpha;
    const float zq = wq / (1.0f + sqrtf(fmaxf(1.0f - wq * wq, 0.0f)));

    // closed-form Chebyshev coeffs of log; PS fold; pre-double H-only
    // entries; all wave-uniform -> SGPR via readfirstlane.
    float cp[30];
    cp[0] = logf(alpha) - log1pf(zq * zq);
    {
      const float tz = -zq;
      float tp = tz;
#pragma unroll
      for (int k = 1; k < 30; ++k) {
        cp[k] = -2.0f * tp * (1.0f / (float)k);
        tp *= tz;
      }
    }
#pragma unroll
    for (int j = 4; j >= 1; --j)
#pragma unroll
      for (int i = 1; i <= 5; ++i) cp[6 * j - i] -= cp[6 * j + i];
#pragma unroll
    for (int k = 0; k < 30; ++k) {
      float v = cp[k];
      if (k >= 7 && (k % 6) != 0) v *= 2.0f;   // H-only coeffs pre-doubled
      cp[k] = rfl(v);
    }
    const float invb = rfl(1.0f / beta);

    // T1 = (M - alpha I)/beta (kept f32 in t1f); S += cp0*I + cp1*T1
    float t1f[16];
#pragma unroll
    for (int r = 0; r < 16; ++r) {
      float v = acc[r];
      if (hasd && r == rd) v -= alpha;
      v *= invb;
      t1f[r] = v;
      Sacc[r] += cp[1] * v;
      if (hasd && r == rd) Sacc[r] += cp[0];
    }
    Split T1S; split16(t1f, T1S);
    Split curS;

    // T2 = 2 T1^2 - I -> LDS0
    acc = prod(T1S, T1S, zero16());
#pragma unroll
    for (int r = 0; r < 16; ++r) {
      float v = 2.0f * acc[r] - ((hasd && r == rd) ? 1.0f : 0.0f);
      tf[r] = v; Sacc[r] += cp[2] * v;
    }
    lwrite(lw, 0, tf);
    split16(tf, curS);

    // T3 = 2 T1*T2 - T1 -> LDS1 (prev = t1f)
    acc = prod(T1S, curS, zero16());
#pragma unroll
    for (int r = 0; r < 16; ++r) {
      float v = 2.0f * acc[r] - t1f[r];
      tf[r] = v; Sacc[r] += cp[3] * v;
    }
    lwrite(lw, 1, tf);
    split16(tf, curS);

    // T4 = 2 T1*T3 - T2 -> LDS2 (prev = LDS0)
    acc = prod(T1S, curS, zero16());
    lread(lw, 0, tf);
#pragma unroll
    for (int r = 0; r < 16; ++r) {
      float v = 2.0f * acc[r] - tf[r];
      tf[r] = v; Sacc[r] += cp[4] * v;
    }
    lwrite(lw, 2, tf);
    split16(tf, curS);

    // T5 = 2 T1*T4 - T3 -> LDS3 (prev = LDS1)
    acc = prod(T1S, curS, zero16());
    lread(lw, 1, tf);
#pragma unroll
    for (int r = 0; r < 16; ++r) {
      float v = 2.0f * acc[r] - tf[r];
      tf[r] = v; Sacc[r] += cp[5] * v;
    }
    lwrite(lw, 3, tf);
    split16(tf, curS);

    // T6 = 2 T1*T5 - T4 (prev = LDS2); keep f32 in t6f
    acc = prod(T1S, curS, zero16());
    float t6f[16];
    lread(lw, 2, tf);
#pragma unroll
    for (int r = 0; r < 16; ++r) {
      float v = 2.0f * acc[r] - tf[r];
      t6f[r] = v; Sacc[r] += cp[6] * v;
    }
    Split T6S; split16(t6f, T6S);

    float hh[16];
    Split HS;

    // j=1: H1; S += T6*H1; T12 = 2 T6^2 - I (keep f32 in t12f)
    hbuild(lw, t1f, cp[7], cp[8], cp[9], cp[10], cp[11], hh);
    split16(hh, HS);
    Sacc = prod(T6S, HS, Sacc);
    acc = prod(T6S, T6S, zero16());
    float t12f[16];
#pragma unroll
    for (int r = 0; r < 16; ++r) {
      float v = 2.0f * acc[r] - ((hasd && r == rd) ? 1.0f : 0.0f);
      t12f[r] = v; Sacc[r] += cp[12] * v;
    }
    split16(t12f, curS);   // T12

    // j=2: H2; S += T12*H2; T18 = 2 T6*T12 - T6
    hbuild(lw, t1f, cp[13], cp[14], cp[15], cp[16], cp[17], hh);
    split16(hh, HS);
    Sacc = prod(curS, HS, Sacc);
    acc = prod(T6S, curS, zero16());
#pragma unroll
    for (int r = 0; r < 16; ++r) {
      float v = 2.0f * acc[r] - t6f[r];
      tf[r] = v; Sacc[r] += cp[18] * v;
    }
    split16(tf, curS);     // T18

    // j=3: H3; S += T18*H3; T24 = 2 T6*T18 - T12
    hbuild(lw, t1f, cp[19], cp[20], cp[21], cp[22], cp[23], hh);
    split16(hh, HS);
    Sacc = prod(curS, HS, Sacc);
    acc = prod(T6S, curS, zero16());
#pragma unroll
    for (int r = 0; r < 16; ++r) {
      float v = 2.0f * acc[r] - t12f[r];
      tf[r] = v; Sacc[r] += cp[24] * v;
    }
    split16(tf, curS);     // T24

    // j=4: H4; S += T24*H4
    hbuild(lw, t1f, cp[25], cp[26], cp[27], cp[28], cp[29], hh);
    split16(hh, HS);
    Sacc = prod(curS, HS, Sacc);
  }

  // partial sum out (row-major; deterministic reduction in stage_c)
  {
    float* dst = partials + (size_t)w * MSZ + 128 * h + col;
#pragma unroll
    for (int r = 0; r < 16; ++r) dst[(((r & 3) + 8 * (r >> 2)) << 5)] = Sacc[r];
  }
}

// ---------------------------------------------------------------------------
// stage_c: per group: L_m; K=sign(L_m) (20 NS iters); E=K*exp(K L_m);
//          C_new = Cp05 * (E * Cp05). (unchanged from R5 — PASSED)
// ---------------------------------------------------------------------------
__global__ void __launch_bounds__(64, 1)
centroid_stage_c(const float* __restrict__ ws, float* __restrict__ out, int sh) {
  __shared__ float lds[5 * MSZ];
  float* Lm = lds;
  float* Ss = lds + MSZ;
  float* Ts = lds + 2 * MSZ;
  float* Us = lds + 3 * MSZ;
  float* Wsl = lds + 4 * MSZ;

  const int lane = threadIdx.x;
  const int lr = lane >> 3, lc = lane & 7;
  const int r0 = lr << 2, c0 = lc << 2;
  const bool dg = (lr == lc);
  const int g = blockIdx.x;
  const int nchunk = 1 << sh;

  float t[4][4];
#pragma unroll
  for (int i = 0; i < 4; ++i)
#pragma unroll
    for (int j = 0; j < 4; ++j) t[i][j] = 0.0f;
  for (int p = 0; p < nchunk; ++p) {
    const float* src = ws + WS_PART + (size_t)((g << sh) + p) * MSZ;
#pragma unroll
    for (int i = 0; i < 4; ++i) {
      const float4 v = *(const float4*)(src + ((r0 + i) << 5) + c0);
      t[i][0] += v.x; t[i][1] += v.y; t[i][2] += v.z; t[i][3] += v.w;
    }
  }
  const float scl = 0.01f / 1024.0f;
#pragma unroll
  for (int i = 0; i < 4; ++i)
#pragma unroll
    for (int j = 0; j < 4; ++j) t[i][j] *= scl;
  twrite(Lm, r0, c0, t);

  float ss = 0.0f;
#pragma unroll
  for (int i = 0; i < 4; ++i)
#pragma unroll
    for (int j = 0; j < 4; ++j) ss += t[i][j] * t[i][j];
  ss = wsum(ss);
  const float innrm = 1.0f / fmaxf(sqrtf(ss), 1e-30f);
  float st[4][4];
#pragma unroll
  for (int i = 0; i < 4; ++i)
#pragma unroll
    for (int j = 0; j < 4; ++j) st[i][j] = t[i][j] * innrm;
  twrite(Ss, r0, c0, st);

  float acc[4][4];

  for (int it = 0; it < 20; ++it) {
    mm32(Ss, Ss, r0, c0, acc);
    wbar();
    twrite(Ts, r0, c0, acc);
    mm32(Ts, Ss, r0, c0, acc);
#pragma unroll
    for (int i = 0; i < 4; ++i)
#pragma unroll
      for (int j = 0; j < 4; ++j) st[i][j] = 1.5f * st[i][j] - 0.5f * acc[i][j];
    wbar();
    twrite(Ss, r0, c0, st);
  }

  float bt[4][4];
  mm32(Ss, Lm, r0, c0, acc);
#pragma unroll
  for (int i = 0; i < 4; ++i)
#pragma unroll
    for (int j = 0; j < 4; ++j) bt[i][j] = acc[i][j];
  wbar();
  twrite(Ts, r0, c0, bt);

  mm32(Ts, Ts, r0, c0, acc);
  twrite(Us, r0, c0, acc);
  {
    float in4[4][4];
#pragma unroll
    for (int i = 0; i < 4; ++i)
#pragma unroll
      for (int j = 0; j < 4; ++j) {
        float v = bt[i][j] * (1.0f / 6.0f) + acc[i][j] * (1.0f / 24.0f);
        if (dg && i == j) v += 0.5f;
        in4[i][j] = v;
      }
    twrite(Wsl, r0, c0, in4);
  }

  mm32(Us, Wsl, r0, c0, acc);
  {
    float pl[4][4];
#pragma unroll
    for (int i = 0; i < 4; ++i)
#pragma unroll
      for (int j = 0; j < 4; ++j) {
        float v = bt[i][j] + acc[i][j];
        if (dg && i == j) v += 1.0f;
        pl[i][j] = v;
      }
    wbar();
    twrite(Us, r0, c0, pl);
  }

  mm32(Ss, Us, r0, c0, acc);
  wbar();
  twrite(Wsl, r0, c0, acc);

  g2l_mat(Ts, ws + WS_CP05 + (size_t)g * MSZ, lane);

  mm32(Wsl, Ts, r0, c0, acc);
  wbar();
  twrite(Us, r0, c0, acc);

  mm32(Ts, Us, r0, c0, acc);
  {
    float* dst = out + (size_t)g * MSZ;
#pragma unroll
    for (int i = 0; i < 4; ++i) {
      float4 v4;
      v4.x = acc[i][0]; v4.y = acc[i][1]; v4.z = acc[i][2]; v4.w = acc[i][3];
      *(float4*)(dst + ((r0 + i) << 5) + c0) = v4;
    }
  }
}

extern "C" void kernel_launch(void* const* d_in, const int* in_sizes, int n_in,
                              void* d_out, int out_size, void* d_ws, size_t ws_size,
                              hipStream_t stream) {
  (void)in_sizes; (void)n_in; (void)out_size;
  const float* X = (const float*)d_in[0];
  const float* C = (const float*)d_in[1];
  const int* idx = (const int*)d_in[2];
  float* out = (float*)d_out;
  float* ws = (float*)d_ws;

  // sh=6: 2048 single-wave blocks (16 jobs each). Fallback sh=5 if ws small.
  const size_t need6 = (size_t)(WS_PART + (NGRP << 6) * MSZ) * sizeof(float);
  const int sh = (ws_size >= need6) ? 6 : 5;
  const int nblk = NGRP << sh;

  hipLaunchKernelGGL(centroid_stage_a, dim3(NGRP), dim3(64), 0, stream, C, ws);
  hipLaunchKernelGGL(centroid_stage_b, dim3(nblk), dim3(64), 0, stream, X, idx, ws,
                     ws + WS_PART, sh);
  hipLaunchKernelGGL(centroid_stage_c, dim3(NGRP), dim3(64), 0, stream, ws, out, sh);
}